// Round 6
// baseline (986.602 us; speedup 1.0000x reference)
//
#include <hip/hip_runtime.h>
#include <stdint.h>

#define N_ELEM 262144
#define NC 512       /* coarse scatter buckets */
#define NFINE 131072 /* fine bins = NC * 256; equal-frequency => lambda ~2 */
#define TILE 8192    /* scatter tile: whole tile counting-sorted in LDS */
#define NBLK (N_ELEM / TILE) /* 32 */
#define CAPW 1024 /* per-wave bucket capacity; equal-freq => ~512 mean */

__device__ __forceinline__ unsigned key_of(float x) {
    unsigned u = __float_as_uint(x);
    return u ^ ((u & 0x80000000u) ? 0xFFFFFFFFu : 0x80000000u);
}
// inverse of key_of (bijective): recover float from order-key
__device__ __forceinline__ float unkey(unsigned k) {
    unsigned u = (k & 0x80000000u) ? (k ^ 0x80000000u) : ~k;
    return __uint_as_float(u);
}

// wave-internal producer->consumer fence through LDS: drain this wave's DS
// ops; "memory" clobber stops compiler motion; sched_barrier(0) pins the
// LLVM scheduler (guide rule #18). One wave per block => no s_barrier ever.
__device__ __forceinline__ void wave_fence() {
    asm volatile("s_waitcnt lgkmcnt(0)" ::: "memory");
    __builtin_amdgcn_sched_barrier(0);
}

// --- Equal-frequency monotone binning ---------------------------------------
// Piecewise-linear approximation of the N(0,1) CDF: 32 segments of width 0.25
// over [-4,4) plus two tail segments. Bins per segment proportional to the
// Gaussian mass of the segment (sum = NFINE exactly). Monotonicity: within a
// segment, (x - x0)*slope with slope>0 then floor then clamp is monotone
// non-decreasing in float arithmetic; across a boundary the clamp bounds
// f <= base[s]+cnt[s]-1 < base[s+1]. Pipeline correctness only needs monotone
// non-decreasing (exact keys order within a fine bin); the distribution
// assumption only affects load balance, and the n>CAPW fallback in
// rank_kernel guards arbitrary inputs.
__device__ __constant__ int d_base[35] = {
    0,      4,      11,     30,     75,     176,    389,    812,    1600,
    2979,   5247,   8752,   13843,  20790,  29699,  40435,  52592,  65536,
    78480,  90637,  101373, 110282, 117229, 122320, 125825, 128093, 129472,
    130260, 130683, 130896, 130997, 131042, 131061, 131068, 131072};
__device__ __constant__ float d_slope[34] = {
    1.0f,     28.0f,    76.0f,    180.0f,   404.0f,   852.0f,   1692.0f,
    3152.0f,  5516.0f,  9072.0f,  14020.0f, 20364.0f, 27788.0f, 35636.0f,
    42944.0f, 48628.0f, 51776.0f, 51776.0f, 48628.0f, 42944.0f, 35636.0f,
    27788.0f, 20364.0f, 14020.0f, 9072.0f,  5516.0f,  3152.0f,  1692.0f,
    852.0f,   404.0f,   180.0f,   76.0f,    28.0f,    1.0f};

__device__ __forceinline__ int fine_of_t(float x, const int* __restrict__ b,
                                         const float* __restrict__ sl) {
    int t = (int)floorf((x + 4.0f) * 4.0f); // saturating cvt: monotone
    int seg = t < 0 ? 0 : (t > 31 ? 33 : t + 1);
    float xlo = (seg == 0)
                    ? -8.0f
                    : ((seg == 33) ? 4.0f : (-4.0f + (float)(seg - 1) * 0.25f));
    int cnt = b[seg + 1] - b[seg];
    int v = (int)floorf((x - xlo) * sl[seg]);
    v = v < 0 ? 0 : (v > cnt - 1 ? cnt - 1 : v);
    return b[seg] + v;
}

// --- Kernel A: per-(rowside,block) histogram of 512 coarse buckets ---------
__global__ __launch_bounds__(256) void hist_kernel(
    const float* __restrict__ pred, const float* __restrict__ tru, int r0,
    unsigned* __restrict__ bh) {
    __shared__ unsigned h[NC];
    __shared__ int tb[35];
    __shared__ float ts[34];
    const int rs = blockIdx.y, blk = blockIdx.x;
    const int row = r0 + (rs >> 1);
    const float* x = (rs & 1) ? tru : pred;
    for (int i = threadIdx.x; i < NC; i += 256) h[i] = 0;
    if (threadIdx.x < 35) tb[threadIdx.x] = d_base[threadIdx.x];
    if (threadIdx.x < 34) ts[threadIdx.x] = d_slope[threadIdx.x];
    __syncthreads();
    const float4* p =
        (const float4*)(x + (size_t)row * N_ELEM + (size_t)blk * TILE);
    for (int i = threadIdx.x; i < TILE / 4; i += 256) {
        float4 v = p[i];
        atomicAdd(&h[fine_of_t(v.x, tb, ts) >> 8], 1u);
        atomicAdd(&h[fine_of_t(v.y, tb, ts) >> 8], 1u);
        atomicAdd(&h[fine_of_t(v.z, tb, ts) >> 8], 1u);
        atomicAdd(&h[fine_of_t(v.w, tb, ts) >> 8], 1u);
    }
    __syncthreads();
    unsigned* out = bh + ((size_t)rs * NBLK + blk) * NC;
    for (int i = threadIdx.x; i < NC; i += 256) out[i] = h[i];
}

// --- Kernel B: per-rowside scan -> per-block scatter starts ----------------
// After this, the blk-0 plane holds the rowside-level coarse exclusive prefix.
__global__ __launch_bounds__(512) void scan_kernel(unsigned* __restrict__ bh) {
    __shared__ unsigned ss[NC];
    const int rs = blockIdx.x;
    unsigned* p = bh + (size_t)rs * NBLK * NC;
    const int c = threadIdx.x; // one thread per coarse bucket
    unsigned cnts[NBLK];
    unsigned tot = 0;
    for (int b = 0; b < NBLK; b++) {
        cnts[b] = p[(size_t)b * NC + c];
        tot += cnts[b];
    }
    ss[c] = tot;
    __syncthreads();
    for (int off = 1; off < NC; off <<= 1) {
        unsigned v = (c >= off) ? ss[c - off] : 0u;
        __syncthreads();
        ss[c] += v;
        __syncthreads();
    }
    unsigned pre = ss[c] - tot; // exclusive
    for (int b = 0; b < NBLK; b++) {
        p[(size_t)b * NC + c] = pre;
        pre += cnts[b];
    }
}

// --- Kernel C: LDS counting-sort scatter -----------------------------------
// The whole 8192-element tile is bucket-sorted in LDS, then written back so
// consecutive threads store consecutive global addresses (runs of ~16 recs
// per bucket => ~128B bursts). This replaced per-lane random 8B stores whose
// 512-line write frontier per block overflowed L2 (R1: WRITE_SIZE 917MB =
// 4.9x ideal; R3: fixed, scatter left the top-5). Bucket id at writeback is
// recovered by inverting the order-key (bijective) through the same table.
__global__ __launch_bounds__(512, 4) void scatter_kernel(
    const float* __restrict__ pred, const float* __restrict__ tru, int r0,
    int RR, const unsigned* __restrict__ bh, uint2* __restrict__ rec) {
    __shared__ unsigned sk[TILE];    // 32 KB sorted keys
    __shared__ unsigned sy[TILE];    // 32 KB sorted payloads
    __shared__ unsigned lh[NC];      // counts -> running cursor
    __shared__ unsigned lstart[NC];  // block-local exclusive prefix
    __shared__ unsigned gst[NC];     // global per-(block,bucket) start
    __shared__ unsigned swave[8];
    __shared__ int tb[35];
    __shared__ float ts[34];
    const int L = blockIdx.x;
    const int xcd = L & 7;
    const int m = L >> 3;
    const int unit = m & (2 * NBLK - 1); // side+blk, 64 units
    const int rowGroup = m >> 6;
    const int crow = rowGroup * 8 + xcd;
    if (crow >= RR) return;
    const int side = unit & 1, blk = unit >> 1;
    const int rs = crow * 2 + side;
    const int row = r0 + crow;
    const float* x = side ? tru : pred;
    const int t = threadIdx.x;
    if (t < NC) lh[t] = 0;
    if (t < 35) tb[t] = d_base[t];
    if (t < 34) ts[t] = d_slope[t];
    __syncthreads();
    const float4* p =
        (const float4*)(x + (size_t)row * N_ELEM + (size_t)blk * TILE);
    const int ib = blk * TILE;
    unsigned ky[16], yy[16];
    // pass 0: load, key, count
#pragma unroll
    for (int i = 0; i < 4; i++) {
        float4 v = p[t + i * 512];
        const int e0 = (t + i * 512) * 4;
        float vv[4] = {v.x, v.y, v.z, v.w};
#pragma unroll
        for (int k = 0; k < 4; k++) {
            float xv = vv[k];
            int f = fine_of_t(xv, tb, ts);
            ky[i * 4 + k] = key_of(xv);
            yy[i * 4 + k] =
                ((unsigned)(f & 255) << 18) | (unsigned)(ib + e0 + k);
            atomicAdd(&lh[f >> 8], 1u);
        }
    }
    __syncthreads();
    // exclusive scan of 512 counts: one thread per bucket, wave shfl scan
    {
        unsigned mine = lh[t];
        unsigned v = mine;
#pragma unroll
        for (int off = 1; off < 64; off <<= 1) {
            unsigned u = (unsigned)__shfl_up((int)v, off, 64);
            if ((t & 63) >= off) v += u;
        }
        if ((t & 63) == 63) swave[t >> 6] = v;
        __syncthreads();
        unsigned wo = 0;
        const int wid = t >> 6;
#pragma unroll
        for (int w = 0; w < 8; w++) wo += (w < wid) ? swave[w] : 0u;
        unsigned ex = v + wo - mine;
        lstart[t] = ex;
        lh[t] = ex; // cursor
        gst[t] = bh[((size_t)rs * NBLK + blk) * NC + t];
    }
    __syncthreads();
    // pass 1: place records bucket-sorted in LDS
#pragma unroll
    for (int i = 0; i < 16; i++) {
        int c = fine_of_t(unkey(ky[i]), tb, ts) >> 8;
        unsigned slot = atomicAdd(&lh[c], 1u);
        sk[slot] = ky[i];
        sy[slot] = yy[i];
    }
    __syncthreads();
    // pass 2: coalesced writeback in sorted order
    uint2* rr = rec + (size_t)rs * N_ELEM;
#pragma unroll
    for (int i = 0; i < 16; i++) {
        const int j = t + i * 512;
        unsigned k = sk[j];
        int c = fine_of_t(unkey(k), tb, ts) >> 8;
        unsigned g = gst[c] + (unsigned)j - lstart[c];
        rr[g] = make_uint2(k, sy[j]);
    }
}

// --- Kernel D: rank. ONE BUCKET = ONE WAVE = ONE 64-THREAD BLOCK. ----------
// R3 (block-per-bucket, 8 barriers): 245us, occ 72%. R5 (4 waves packed per
// block, 25KB LDS): 322us, occ 46% — packing halved blocks/CU; TLP is the
// first-order term for this latency-bound kernel. This version keeps R5's
// zero-barrier wave-private structure but gives each wave its OWN block:
// 6.2KB LDS/block => ~26 independent waves/CU (~81% occ), no s_barrier.
// side1 prefetches rp[idx] at record-load time (issue-early, T14).
template <int SIDE>
__global__ __launch_bounds__(64) void rank_kernel(
    const uint2* __restrict__ rec, const unsigned* __restrict__ bh,
    unsigned* __restrict__ rp0, unsigned long long* __restrict__ S, int r0,
    int RR) {
    __shared__ unsigned sk[CAPW];  // 4 KB sorted keys
    __shared__ unsigned cnt[256];  // 1 KB counts -> cursors
    __shared__ unsigned bas[260];  // sub-bin starts (260: 16B-multiple)
    const int L = blockIdx.x;
    const int xcd = L & 7;
    const int m = L >> 3;
    const int c = m & (NC - 1);
    const int rowGroup = m >> 9; // m / NC
    const int crow = rowGroup * 8 + xcd;
    if (crow >= RR) return;
    const int lane = threadIdx.x;
    const int rs = crow * 2 + SIDE;
    const unsigned* pf = bh + (size_t)rs * NBLK * NC; // blk0 = rowside prefix
    const unsigned base = pf[c];
    const unsigned end = (c + 1 < NC) ? pf[c + 1] : (unsigned)N_ELEM;
    const int n = (int)(end - base);
    const uint2* r = rec + (size_t)rs * N_ELEM + base;
    unsigned* rp = rp0 + (size_t)crow * N_ELEM;
    unsigned long long acc = 0;

    if (n > 0 && n <= CAPW) {
        ((uint4*)cnt)[lane] = make_uint4(0u, 0u, 0u, 0u);
        wave_fence();
        unsigned ky[16], yy[16], sl[16], rv[16];
        // phase 1: load records (coalesced), histogram sub-bins, and (SIDE=1)
        // issue the rp gathers early — latency hides under phases 2-4.
#pragma unroll
        for (int j = 0; j < 16; j++) {
            const int p = lane + j * 64;
            if (p < n) {
                uint2 e = r[p];
                ky[j] = e.x;
                yy[j] = e.y;
                if (SIDE) rv[j] = rp[e.y & 0x3FFFFu];
                atomicAdd(&cnt[(e.y >> 18) & 255], 1u);
            }
        }
        wave_fence();
        // phase 2: exclusive scan of 256 sub-bin counts, 4 per lane + wave
        // shfl scan — single wave, no cross-wave stage.
        {
            uint4 c4 = ((const uint4*)cnt)[lane];
            unsigned tot = c4.x + c4.y + c4.z + c4.w;
            unsigned v = tot;
#pragma unroll
            for (int off = 1; off < 64; off <<= 1) {
                unsigned u = (unsigned)__shfl_up((int)v, off, 64);
                if (lane >= off) v += u;
            }
            unsigned ex = v - tot;
            uint4 b4 = make_uint4(ex, ex + c4.x, ex + c4.x + c4.y,
                                  ex + c4.x + c4.y + c4.z);
            ((uint4*)bas)[lane] = b4;
            ((uint4*)cnt)[lane] = b4; // cursor re-init
            if (lane == 63) bas[256] = (unsigned)n;
        }
        wave_fence();
        // phase 3: counting-sort placement of keys only
#pragma unroll
        for (int j = 0; j < 16; j++) {
            const int p = lane + j * 64;
            if (p < n) {
                unsigned sub = (yy[j] >> 18) & 255;
                unsigned slot = atomicAdd(&cnt[sub], 1u);
                sl[j] = slot;
                sk[slot] = ky[j];
            }
        }
        wave_fence();
        // phase 4: exact in-sub-bin ordinal rank (~2 compares/elem, lambda~2)
#pragma unroll
        for (int j = 0; j < 16; j++) {
            const int p = lane + j * 64;
            if (p < n) {
                unsigned sub = (yy[j] >> 18) & 255;
                unsigned lo = bas[sub], hi = bas[sub + 1];
                unsigned myKey = ky[j], slot = sl[j];
                unsigned cb = 0;
                for (unsigned k = lo; k < hi; k++) {
                    unsigned K = sk[k];
                    cb += (K < myKey || (K == myKey && k < slot)) ? 1u : 0u;
                }
                unsigned rank = base + lo + cb + 1u;
                if (!SIDE)
                    rp[yy[j] & 0x3FFFFu] = rank;
                else
                    acc += (unsigned long long)rv[j] * (unsigned long long)rank;
            }
        }
    } else if (n > CAPW) { // wave-serial exact fallback (not expected)
        for (int p = lane; p < n; p += 64) {
            uint2 e = r[p];
            unsigned sub = (e.y >> 18) & 255;
            unsigned cb = 0;
            for (int k = 0; k < n; k++) {
                uint2 ek = r[k];
                unsigned s2 = (ek.y >> 18) & 255;
                bool less =
                    (s2 < sub) ||
                    (s2 == sub && (ek.x < e.x || (ek.x == e.x && k < p)));
                cb += less ? 1u : 0u;
            }
            unsigned rank = base + cb + 1u;
            unsigned idx = e.y & 0x3FFFFu;
            if (!SIDE)
                rp[idx] = rank;
            else
                acc += (unsigned long long)rp[idx] * (unsigned long long)rank;
        }
    }
    if (SIDE) {
#pragma unroll
        for (int off = 32; off > 0; off >>= 1)
            acc += __shfl_down(acc, off, 64);
        if (lane == 0 && acc) atomicAdd(&S[r0 + crow], acc);
    }
}

// --- Kernel E: closed-form Pearson of two exact permutations + loss --------
__global__ void finalize_kernel(const unsigned long long* __restrict__ S, int B,
                                float* __restrict__ out) {
    __shared__ double sh[128];
    const int t = threadIdx.x;
    const double Nd = (double)N_ELEM;
    const double m = (Nd + 1.0) * 0.5;
    const double q = Nd * (Nd * Nd - 1.0) / 12.0;
    double c = 0.0;
    if (t < B) {
        double num = (double)(long long)S[t] - Nd * m * m;
        c = num / sqrt(q * q + 1e-8);
    }
    sh[t] = c;
    __syncthreads();
    for (int off = 64; off > 0; off >>= 1) {
        if (t < off) sh[t] += sh[t + off];
        __syncthreads();
    }
    double mean = sh[0] / (double)B;
    __syncthreads();
    double d = (t < B) ? (c - mean) : 0.0;
    sh[t] = d * d;
    __syncthreads();
    for (int off = 64; off > 0; off >>= 1) {
        if (t < off) sh[t] += sh[t + off];
        __syncthreads();
    }
    if (t == 0) {
        double var = sh[0] / (double)B;
        double stdv = sqrt(var) + 1e-8;
        double icir = mean / stdv;
        out[0] = (float)(-icir + 0.1 * stdv);
    }
}

extern "C" void kernel_launch(void* const* d_in, const int* in_sizes, int n_in,
                              void* d_out, int out_size, void* d_ws,
                              size_t ws_size, hipStream_t stream) {
    const float* pred = (const float*)d_in[0];
    const float* tru = (const float*)d_in[1];
    const int B = in_sizes[0] / N_ELEM; // 90

    char* ws = (char*)d_ws;
    unsigned long long* S = (unsigned long long*)ws;
    const size_t off0 = 4096;
    // per chunked row: bh 2*32*512*4 = 128KB, rec both sides 4MB, rp0 1MB
    const size_t bhRow = (size_t)2 * NBLK * NC * 4;
    const size_t recRow = (size_t)2 * N_ELEM * 8;
    const size_t rpRow = (size_t)N_ELEM * 4;
    const size_t perRow = bhRow + recRow + rpRow;
    int R = (int)((ws_size > off0 ? ws_size - off0 : 0) / perRow);
    if (R > B) R = B;
    if (R < 1) R = 1;

    unsigned* bh = (unsigned*)(ws + off0);
    uint2* rec = (uint2*)(ws + off0 + (size_t)R * bhRow);
    unsigned* rp0 = (unsigned*)(ws + off0 + (size_t)R * bhRow + (size_t)R * recRow);

    hipMemsetAsync(S, 0, (size_t)B * 8, stream);

    for (int r0 = 0; r0 < B; r0 += R) {
        int RR = (B - r0 < R) ? (B - r0) : R;
        int rowGroups = (RR + 7) / 8;
        hist_kernel<<<dim3(NBLK, 2 * RR), 256, 0, stream>>>(pred, tru, r0, bh);
        scan_kernel<<<2 * RR, NC, 0, stream>>>(bh);
        scatter_kernel<<<rowGroups * 2 * NBLK * 8, 512, 0, stream>>>(
            pred, tru, r0, RR, bh, rec);
        rank_kernel<0><<<rowGroups * NC * 8, 64, 0, stream>>>(rec, bh, rp0, S,
                                                              r0, RR);
        rank_kernel<1><<<rowGroups * NC * 8, 64, 0, stream>>>(rec, bh, rp0, S,
                                                              r0, RR);
    }
    finalize_kernel<<<1, 128, 0, stream>>>(S, B, (float*)d_out);
}

// Round 7
// 780.831 us; speedup vs baseline: 1.2635x; 1.2635x over previous
//
#include <hip/hip_runtime.h>
#include <stdint.h>

#define N_ELEM 262144
#define NC 512       /* coarse scatter buckets */
#define NFINE 131072 /* fine bins = NC * 256; equal-frequency => lambda ~2 */
#define TILE 8192    /* scatter tile: whole tile counting-sorted in LDS */
#define NBLK (N_ELEM / TILE) /* 32 */
#define CAPW 1024 /* per-wave bucket capacity; equal-freq => ~512 mean */

__device__ __forceinline__ unsigned key_of(float x) {
    unsigned u = __float_as_uint(x);
    return u ^ ((u & 0x80000000u) ? 0xFFFFFFFFu : 0x80000000u);
}
// inverse of key_of (bijective): recover float from order-key
__device__ __forceinline__ float unkey(unsigned k) {
    unsigned u = (k & 0x80000000u) ? (k ^ 0x80000000u) : ~k;
    return __uint_as_float(u);
}

// wave-internal producer->consumer fence through LDS: drain this wave's DS
// ops; "memory" clobber stops compiler motion; sched_barrier(0) pins the
// LLVM scheduler (guide rule #18). One wave per block => no s_barrier ever.
__device__ __forceinline__ void wave_fence() {
    asm volatile("s_waitcnt lgkmcnt(0)" ::: "memory");
    __builtin_amdgcn_sched_barrier(0);
}

// --- Equal-frequency monotone binning ---------------------------------------
// Piecewise-linear approximation of the N(0,1) CDF: 32 segments of width 0.25
// over [-4,4) plus two tail segments. Bins per segment proportional to the
// Gaussian mass of the segment (sum = NFINE exactly). Monotonicity: within a
// segment, (x - x0)*slope with slope>0 then floor then clamp is monotone
// non-decreasing in float arithmetic; across a boundary the clamp bounds
// f <= base[s]+cnt[s]-1 < base[s+1]. Pipeline correctness only needs monotone
// non-decreasing (exact keys order within a fine bin); the distribution
// assumption only affects load balance, and the n>CAPW fallback in
// rank_kernel guards arbitrary inputs.
__device__ __constant__ int d_base[35] = {
    0,      4,      11,     30,     75,     176,    389,    812,    1600,
    2979,   5247,   8752,   13843,  20790,  29699,  40435,  52592,  65536,
    78480,  90637,  101373, 110282, 117229, 122320, 125825, 128093, 129472,
    130260, 130683, 130896, 130997, 131042, 131061, 131068, 131072};
__device__ __constant__ float d_slope[34] = {
    1.0f,     28.0f,    76.0f,    180.0f,   404.0f,   852.0f,   1692.0f,
    3152.0f,  5516.0f,  9072.0f,  14020.0f, 20364.0f, 27788.0f, 35636.0f,
    42944.0f, 48628.0f, 51776.0f, 51776.0f, 48628.0f, 42944.0f, 35636.0f,
    27788.0f, 20364.0f, 14020.0f, 9072.0f,  5516.0f,  3152.0f,  1692.0f,
    852.0f,   404.0f,   180.0f,   76.0f,    28.0f,    1.0f};

__device__ __forceinline__ int fine_of_t(float x, const int* __restrict__ b,
                                         const float* __restrict__ sl) {
    int t = (int)floorf((x + 4.0f) * 4.0f); // saturating cvt: monotone
    int seg = t < 0 ? 0 : (t > 31 ? 33 : t + 1);
    float xlo = (seg == 0)
                    ? -8.0f
                    : ((seg == 33) ? 4.0f : (-4.0f + (float)(seg - 1) * 0.25f));
    int cnt = b[seg + 1] - b[seg];
    int v = (int)floorf((x - xlo) * sl[seg]);
    v = v < 0 ? 0 : (v > cnt - 1 ? cnt - 1 : v);
    return b[seg] + v;
}

// --- Kernel A: per-(rowside,block) histogram of 512 coarse buckets ---------
__global__ __launch_bounds__(256) void hist_kernel(
    const float* __restrict__ pred, const float* __restrict__ tru, int r0,
    unsigned* __restrict__ bh) {
    __shared__ unsigned h[NC];
    __shared__ int tb[35];
    __shared__ float ts[34];
    const int rs = blockIdx.y, blk = blockIdx.x;
    const int row = r0 + (rs >> 1);
    const float* x = (rs & 1) ? tru : pred;
    for (int i = threadIdx.x; i < NC; i += 256) h[i] = 0;
    if (threadIdx.x < 35) tb[threadIdx.x] = d_base[threadIdx.x];
    if (threadIdx.x < 34) ts[threadIdx.x] = d_slope[threadIdx.x];
    __syncthreads();
    const float4* p =
        (const float4*)(x + (size_t)row * N_ELEM + (size_t)blk * TILE);
    for (int i = threadIdx.x; i < TILE / 4; i += 256) {
        float4 v = p[i];
        atomicAdd(&h[fine_of_t(v.x, tb, ts) >> 8], 1u);
        atomicAdd(&h[fine_of_t(v.y, tb, ts) >> 8], 1u);
        atomicAdd(&h[fine_of_t(v.z, tb, ts) >> 8], 1u);
        atomicAdd(&h[fine_of_t(v.w, tb, ts) >> 8], 1u);
    }
    __syncthreads();
    unsigned* out = bh + ((size_t)rs * NBLK + blk) * NC;
    for (int i = threadIdx.x; i < NC; i += 256) out[i] = h[i];
}

// --- Kernel B: per-rowside scan -> per-block scatter starts ----------------
// After this, the blk-0 plane holds the rowside-level coarse exclusive prefix.
__global__ __launch_bounds__(512) void scan_kernel(unsigned* __restrict__ bh) {
    __shared__ unsigned ss[NC];
    const int rs = blockIdx.x;
    unsigned* p = bh + (size_t)rs * NBLK * NC;
    const int c = threadIdx.x; // one thread per coarse bucket
    unsigned cnts[NBLK];
    unsigned tot = 0;
    for (int b = 0; b < NBLK; b++) {
        cnts[b] = p[(size_t)b * NC + c];
        tot += cnts[b];
    }
    ss[c] = tot;
    __syncthreads();
    for (int off = 1; off < NC; off <<= 1) {
        unsigned v = (c >= off) ? ss[c - off] : 0u;
        __syncthreads();
        ss[c] += v;
        __syncthreads();
    }
    unsigned pre = ss[c] - tot; // exclusive
    for (int b = 0; b < NBLK; b++) {
        p[(size_t)b * NC + c] = pre;
        pre += cnts[b];
    }
}

// --- Kernel C: LDS counting-sort scatter -----------------------------------
// The whole 8192-element tile is bucket-sorted in LDS, then written back so
// consecutive threads store consecutive global addresses (runs of ~16 recs
// per bucket => ~128B bursts). This replaced per-lane random 8B stores whose
// 512-line write frontier per block overflowed L2 (R1: WRITE_SIZE 917MB =
// 4.9x ideal; R3: fixed, scatter left the top-5). Bucket id at writeback is
// recovered by inverting the order-key (bijective) through the same table.
__global__ __launch_bounds__(512, 4) void scatter_kernel(
    const float* __restrict__ pred, const float* __restrict__ tru, int r0,
    int RR, const unsigned* __restrict__ bh, uint2* __restrict__ rec) {
    __shared__ unsigned sk[TILE];    // 32 KB sorted keys
    __shared__ unsigned sy[TILE];    // 32 KB sorted payloads
    __shared__ unsigned lh[NC];      // counts -> running cursor
    __shared__ unsigned lstart[NC];  // block-local exclusive prefix
    __shared__ unsigned gst[NC];     // global per-(block,bucket) start
    __shared__ unsigned swave[8];
    __shared__ int tb[35];
    __shared__ float ts[34];
    const int L = blockIdx.x;
    const int xcd = L & 7;
    const int m = L >> 3;
    const int unit = m & (2 * NBLK - 1); // side+blk, 64 units
    const int rowGroup = m >> 6;
    const int crow = rowGroup * 8 + xcd;
    if (crow >= RR) return;
    const int side = unit & 1, blk = unit >> 1;
    const int rs = crow * 2 + side;
    const int row = r0 + crow;
    const float* x = side ? tru : pred;
    const int t = threadIdx.x;
    if (t < NC) lh[t] = 0;
    if (t < 35) tb[t] = d_base[t];
    if (t < 34) ts[t] = d_slope[t];
    __syncthreads();
    const float4* p =
        (const float4*)(x + (size_t)row * N_ELEM + (size_t)blk * TILE);
    const int ib = blk * TILE;
    unsigned ky[16], yy[16];
    // pass 0: load, key, count
#pragma unroll
    for (int i = 0; i < 4; i++) {
        float4 v = p[t + i * 512];
        const int e0 = (t + i * 512) * 4;
        float vv[4] = {v.x, v.y, v.z, v.w};
#pragma unroll
        for (int k = 0; k < 4; k++) {
            float xv = vv[k];
            int f = fine_of_t(xv, tb, ts);
            ky[i * 4 + k] = key_of(xv);
            yy[i * 4 + k] =
                ((unsigned)(f & 255) << 18) | (unsigned)(ib + e0 + k);
            atomicAdd(&lh[f >> 8], 1u);
        }
    }
    __syncthreads();
    // exclusive scan of 512 counts: one thread per bucket, wave shfl scan
    {
        unsigned mine = lh[t];
        unsigned v = mine;
#pragma unroll
        for (int off = 1; off < 64; off <<= 1) {
            unsigned u = (unsigned)__shfl_up((int)v, off, 64);
            if ((t & 63) >= off) v += u;
        }
        if ((t & 63) == 63) swave[t >> 6] = v;
        __syncthreads();
        unsigned wo = 0;
        const int wid = t >> 6;
#pragma unroll
        for (int w = 0; w < 8; w++) wo += (w < wid) ? swave[w] : 0u;
        unsigned ex = v + wo - mine;
        lstart[t] = ex;
        lh[t] = ex; // cursor
        gst[t] = bh[((size_t)rs * NBLK + blk) * NC + t];
    }
    __syncthreads();
    // pass 1: place records bucket-sorted in LDS
#pragma unroll
    for (int i = 0; i < 16; i++) {
        int c = fine_of_t(unkey(ky[i]), tb, ts) >> 8;
        unsigned slot = atomicAdd(&lh[c], 1u);
        sk[slot] = ky[i];
        sy[slot] = yy[i];
    }
    __syncthreads();
    // pass 2: coalesced writeback in sorted order
    uint2* rr = rec + (size_t)rs * N_ELEM;
#pragma unroll
    for (int i = 0; i < 16; i++) {
        const int j = t + i * 512;
        unsigned k = sk[j];
        int c = fine_of_t(unkey(k), tb, ts) >> 8;
        unsigned g = gst[c] + (unsigned)j - lstart[c];
        rr[g] = make_uint2(k, sy[j]);
    }
}

// --- Kernel D: rank. One bucket = one wave = one 64-thread block. ----------
// R6 evidence: side1 (rank + random rp[idx] GATHER) = 317us/dispatch; side0
// (identical rank + random rp[idx] WRITE) never entered the top-5 (~3-5x
// cheaper). The random 4B gather (512 distinct L2 lines per wave) was the
// wall, not barriers/occupancy. So BOTH sides now only WRITE their rank
// array (scatter writes are fire-and-forget, L2 write-combined); the
// rp x rt join moves to dot_kernel's coalesced stream.
template <int SIDE>
__global__ __launch_bounds__(64) void rank_kernel(
    const uint2* __restrict__ rec, const unsigned* __restrict__ bh,
    unsigned* __restrict__ outArr, int r0, int RR) {
    __shared__ unsigned sk[CAPW];  // 4 KB sorted keys
    __shared__ unsigned cnt[256];  // 1 KB counts -> cursors
    __shared__ unsigned bas[260];  // sub-bin starts (260: 16B-multiple)
    const int L = blockIdx.x;
    const int xcd = L & 7;
    const int m = L >> 3;
    const int c = m & (NC - 1);
    const int rowGroup = m >> 9; // m / NC
    const int crow = rowGroup * 8 + xcd;
    if (crow >= RR) return;
    const int lane = threadIdx.x;
    const int rs = crow * 2 + SIDE;
    const unsigned* pf = bh + (size_t)rs * NBLK * NC; // blk0 = rowside prefix
    const unsigned base = pf[c];
    const unsigned end = (c + 1 < NC) ? pf[c + 1] : (unsigned)N_ELEM;
    const int n = (int)(end - base);
    const uint2* r = rec + (size_t)rs * N_ELEM + base;
    unsigned* out = outArr + (size_t)crow * N_ELEM;

    if (n > 0 && n <= CAPW) {
        ((uint4*)cnt)[lane] = make_uint4(0u, 0u, 0u, 0u);
        wave_fence();
        unsigned ky[16], yy[16], sl[16];
        // phase 1: load records (coalesced), histogram sub-bins
#pragma unroll
        for (int j = 0; j < 16; j++) {
            const int p = lane + j * 64;
            if (p < n) {
                uint2 e = r[p];
                ky[j] = e.x;
                yy[j] = e.y;
                atomicAdd(&cnt[(e.y >> 18) & 255], 1u);
            }
        }
        wave_fence();
        // phase 2: exclusive scan of 256 sub-bin counts, 4 per lane + wave
        // shfl scan — single wave, no cross-wave stage.
        {
            uint4 c4 = ((const uint4*)cnt)[lane];
            unsigned tot = c4.x + c4.y + c4.z + c4.w;
            unsigned v = tot;
#pragma unroll
            for (int off = 1; off < 64; off <<= 1) {
                unsigned u = (unsigned)__shfl_up((int)v, off, 64);
                if (lane >= off) v += u;
            }
            unsigned ex = v - tot;
            uint4 b4 = make_uint4(ex, ex + c4.x, ex + c4.x + c4.y,
                                  ex + c4.x + c4.y + c4.z);
            ((uint4*)bas)[lane] = b4;
            ((uint4*)cnt)[lane] = b4; // cursor re-init
            if (lane == 63) bas[256] = (unsigned)n;
        }
        wave_fence();
        // phase 3: counting-sort placement of keys only
#pragma unroll
        for (int j = 0; j < 16; j++) {
            const int p = lane + j * 64;
            if (p < n) {
                unsigned sub = (yy[j] >> 18) & 255;
                unsigned slot = atomicAdd(&cnt[sub], 1u);
                sl[j] = slot;
                sk[slot] = ky[j];
            }
        }
        wave_fence();
        // phase 4: exact in-sub-bin ordinal rank (~2 compares/elem, lambda~2)
        // then WRITE rank to out[idx] (no gather).
#pragma unroll
        for (int j = 0; j < 16; j++) {
            const int p = lane + j * 64;
            if (p < n) {
                unsigned sub = (yy[j] >> 18) & 255;
                unsigned lo = bas[sub], hi = bas[sub + 1];
                unsigned myKey = ky[j], slot = sl[j];
                unsigned cb = 0;
                for (unsigned k = lo; k < hi; k++) {
                    unsigned K = sk[k];
                    cb += (K < myKey || (K == myKey && k < slot)) ? 1u : 0u;
                }
                out[yy[j] & 0x3FFFFu] = base + lo + cb + 1u;
            }
        }
    } else if (n > CAPW) { // wave-serial exact fallback (not expected)
        for (int p = lane; p < n; p += 64) {
            uint2 e = r[p];
            unsigned sub = (e.y >> 18) & 255;
            unsigned cb = 0;
            for (int k = 0; k < n; k++) {
                uint2 ek = r[k];
                unsigned s2 = (ek.y >> 18) & 255;
                bool less =
                    (s2 < sub) ||
                    (s2 == sub && (ek.x < e.x || (ek.x == e.x && k < p)));
                cb += less ? 1u : 0u;
            }
            out[e.y & 0x3FFFFu] = base + cb + 1u;
        }
    }
}

// --- Kernel D2: coalesced dot of the two rank arrays -> S[row] -------------
// Streams rp/rt linearly (uint4), ull accumulate, one atomic per block.
__global__ __launch_bounds__(256) void dot_kernel(
    const unsigned* __restrict__ rp0, const unsigned* __restrict__ rt0,
    unsigned long long* __restrict__ S, int r0, int RR) {
    const int L = blockIdx.x;
    const int xcd = L & 7;
    const int q = L >> 3;
    const int seg = q & 15; // 16 segments x 16384 elements
    const int rowGroup = q >> 4;
    const int crow = rowGroup * 8 + xcd;
    if (crow >= RR) return;
    const int t = threadIdx.x;
    const size_t off = (size_t)crow * N_ELEM + (size_t)seg * (N_ELEM / 16);
    const uint4* a = (const uint4*)(rp0 + off);
    const uint4* b = (const uint4*)(rt0 + off);
    unsigned long long acc = 0;
    for (int i = t; i < (N_ELEM / 16) / 4; i += 256) {
        uint4 x = a[i], y = b[i];
        acc += (unsigned long long)x.x * y.x + (unsigned long long)x.y * y.y +
               (unsigned long long)x.z * y.z + (unsigned long long)x.w * y.w;
    }
#pragma unroll
    for (int off2 = 32; off2 > 0; off2 >>= 1)
        acc += __shfl_down(acc, off2, 64);
    __shared__ unsigned long long red[4];
    if ((t & 63) == 0) red[t >> 6] = acc;
    __syncthreads();
    if (t == 0) {
        unsigned long long s = red[0] + red[1] + red[2] + red[3];
        if (s) atomicAdd(&S[r0 + crow], s);
    }
}

// --- Kernel E: closed-form Pearson of two exact permutations + loss --------
__global__ void finalize_kernel(const unsigned long long* __restrict__ S, int B,
                                float* __restrict__ out) {
    __shared__ double sh[128];
    const int t = threadIdx.x;
    const double Nd = (double)N_ELEM;
    const double m = (Nd + 1.0) * 0.5;
    const double q = Nd * (Nd * Nd - 1.0) / 12.0;
    double c = 0.0;
    if (t < B) {
        double num = (double)(long long)S[t] - Nd * m * m;
        c = num / sqrt(q * q + 1e-8);
    }
    sh[t] = c;
    __syncthreads();
    for (int off = 64; off > 0; off >>= 1) {
        if (t < off) sh[t] += sh[t + off];
        __syncthreads();
    }
    double mean = sh[0] / (double)B;
    __syncthreads();
    double d = (t < B) ? (c - mean) : 0.0;
    sh[t] = d * d;
    __syncthreads();
    for (int off = 64; off > 0; off >>= 1) {
        if (t < off) sh[t] += sh[t + off];
        __syncthreads();
    }
    if (t == 0) {
        double var = sh[0] / (double)B;
        double stdv = sqrt(var) + 1e-8;
        double icir = mean / stdv;
        out[0] = (float)(-icir + 0.1 * stdv);
    }
}

extern "C" void kernel_launch(void* const* d_in, const int* in_sizes, int n_in,
                              void* d_out, int out_size, void* d_ws,
                              size_t ws_size, hipStream_t stream) {
    const float* pred = (const float*)d_in[0];
    const float* tru = (const float*)d_in[1];
    const int B = in_sizes[0] / N_ELEM; // 90

    char* ws = (char*)d_ws;
    unsigned long long* S = (unsigned long long*)ws;
    const size_t off0 = 4096;
    // per chunked row: bh 128KB, rec both sides 4MB, rp 1MB, rt 1MB
    const size_t bhRow = (size_t)2 * NBLK * NC * 4;
    const size_t recRow = (size_t)2 * N_ELEM * 8;
    const size_t rpRow = (size_t)N_ELEM * 4;
    const size_t perRow = bhRow + recRow + 2 * rpRow;
    int R = (int)((ws_size > off0 ? ws_size - off0 : 0) / perRow);
    if (R > B) R = B;
    if (R < 1) R = 1;

    unsigned* bh = (unsigned*)(ws + off0);
    uint2* rec = (uint2*)(ws + off0 + (size_t)R * bhRow);
    unsigned* rp0 =
        (unsigned*)(ws + off0 + (size_t)R * bhRow + (size_t)R * recRow);
    unsigned* rt0 = rp0 + (size_t)R * N_ELEM;

    hipMemsetAsync(S, 0, (size_t)B * 8, stream);

    for (int r0 = 0; r0 < B; r0 += R) {
        int RR = (B - r0 < R) ? (B - r0) : R;
        int rowGroups = (RR + 7) / 8;
        hist_kernel<<<dim3(NBLK, 2 * RR), 256, 0, stream>>>(pred, tru, r0, bh);
        scan_kernel<<<2 * RR, NC, 0, stream>>>(bh);
        scatter_kernel<<<rowGroups * 2 * NBLK * 8, 512, 0, stream>>>(
            pred, tru, r0, RR, bh, rec);
        rank_kernel<0><<<rowGroups * NC * 8, 64, 0, stream>>>(rec, bh, rp0,
                                                              r0, RR);
        rank_kernel<1><<<rowGroups * NC * 8, 64, 0, stream>>>(rec, bh, rt0,
                                                              r0, RR);
        dot_kernel<<<rowGroups * 16 * 8, 256, 0, stream>>>(rp0, rt0, S, r0,
                                                           RR);
    }
    finalize_kernel<<<1, 128, 0, stream>>>(S, B, (float*)d_out);
}